// Round 1
// baseline (290.111 us; speedup 1.0000x reference)
//
#include <hip/hip_runtime.h>
#include <hip/hip_bf16.h>
#include <stdint.h>

#define NN 2048

typedef __bf16 bf16;
typedef __bf16 bf16x8 __attribute__((ext_vector_type(8)));
typedef __bf16 bf16x4 __attribute__((ext_vector_type(4)));
typedef float f32x4 __attribute__((ext_vector_type(4)));

// ---------------------------------------------------------------------------
// async global->LDS, 16B per lane (wave-uniform LDS base + lane*16 semantics)
// ---------------------------------------------------------------------------
__device__ __forceinline__ void async_copy16(bf16* lds, const bf16* g) {
    __builtin_amdgcn_global_load_lds(
        (const __attribute__((address_space(1))) unsigned int*)g,
        (__attribute__((address_space(3))) unsigned int*)lds,
        16, 0, 0);
}

// ---------------------------------------------------------------------------
// fp32 -> bf16 transpose cast (and optional non-transposed bf16 copy).
// outT[r][c] = (bf16) in[c][r];  outN[i] = (bf16) in[i] if outN != null
// block (32,8), grid (64,64)
// ---------------------------------------------------------------------------
__global__ void transpose_cast_kernel(const float* __restrict__ in,
                                      bf16* __restrict__ outT,
                                      bf16* __restrict__ outN) {
    __shared__ float tile[32][33];
    const int bx = blockIdx.x * 32, by = blockIdx.y * 32;
    const int tx = threadIdx.x, ty = threadIdx.y;
#pragma unroll
    for (int i = 0; i < 32; i += 8) {
        float v = in[(size_t)(by + ty + i) * NN + bx + tx];
        tile[ty + i][tx] = v;
        if (outN) outN[(size_t)(by + ty + i) * NN + bx + tx] = (bf16)v;
    }
    __syncthreads();
#pragma unroll
    for (int i = 0; i < 32; i += 8)
        outT[(size_t)(bx + ty + i) * NN + by + tx] = (bf16)tile[tx][ty + i];
}

// ---------------------------------------------------------------------------
// Batched GEMM: C = A(row-major bf16) @ B, with B given as Bt = B^T row-major
// (i.e. Bt[n][k]).  C fp32 row-major.  blockIdx.z selects the GEMM.
// 128x128 tile, BK=32, 256 threads = 4 waves, each wave 64x64 via 4x4 MFMAs.
// ---------------------------------------------------------------------------
struct GemmArgs {
    const bf16* A[3];
    const bf16* Bt[3];
    float*      C[3];
};

__global__ __launch_bounds__(256) void gemm_bt_batched(GemmArgs args) {
    const bf16* __restrict__ A  = args.A[blockIdx.z];
    const bf16* __restrict__ Bt = args.Bt[blockIdx.z];
    float* __restrict__ C       = args.C[blockIdx.z];

    __shared__ bf16 As[128 * 32];
    __shared__ bf16 Bs[128 * 32];

    const int t    = threadIdx.x;        // 0..255
    const int bm   = blockIdx.x * 128;
    const int bn   = blockIdx.y * 128;

    // staging map: element offset (r*256+t)*8 -> row=off>>5, col=off&31
    const int off0 = t * 8;
    const int row0 = off0 >> 5;          // 0..63
    const int col0 = off0 & 31;

    const bf16* gA0 = A  + (size_t)(bm + row0) * NN + col0;
    const bf16* gB0 = Bt + (size_t)(bn + row0) * NN + col0;

    const int wave = t >> 6;
    const int lane = t & 63;
    const int wm   = (wave >> 1) * 64;   // wave row offset in tile
    const int wn   = (wave & 1) * 64;    // wave col offset in tile
    const int lrow = lane & 15;
    const int q    = lane >> 4;          // quad 0..3

    f32x4 acc[4][4];
#pragma unroll
    for (int i = 0; i < 4; ++i)
#pragma unroll
        for (int j = 0; j < 4; ++j) acc[i][j] = (f32x4){0.f, 0.f, 0.f, 0.f};

    for (int k0 = 0; k0 < NN; k0 += 32) {
        async_copy16(&As[off0],            gA0 + k0);
        async_copy16(&As[off0 + 64 * 32],  gA0 + (size_t)64 * NN + k0);
        async_copy16(&Bs[off0],            gB0 + k0);
        async_copy16(&Bs[off0 + 64 * 32],  gB0 + (size_t)64 * NN + k0);
        __syncthreads();

        bf16x8 af[4], bfr[4];
#pragma unroll
        for (int i = 0; i < 4; ++i)
            af[i] = *(const bf16x8*)&As[(wm + i * 16 + lrow) * 32 + q * 8];
#pragma unroll
        for (int j = 0; j < 4; ++j)
            bfr[j] = *(const bf16x8*)&Bs[(wn + j * 16 + lrow) * 32 + q * 8];

#pragma unroll
        for (int i = 0; i < 4; ++i)
#pragma unroll
            for (int j = 0; j < 4; ++j)
                acc[i][j] = __builtin_amdgcn_mfma_f32_16x16x32_bf16(
                    af[i], bfr[j], acc[i][j], 0, 0, 0);
        __syncthreads();
    }

    // C/D layout: col = lane&15, row = q*4 + reg
#pragma unroll
    for (int i = 0; i < 4; ++i)
#pragma unroll
        for (int j = 0; j < 4; ++j)
#pragma unroll
            for (int r = 0; r < 4; ++r)
                C[(size_t)(bm + wm + i * 16 + q * 4 + r) * NN +
                  (bn + wn + j * 16 + lrow)] = acc[i][j][r];
}

// ---------------------------------------------------------------------------
// M1 post-pass: M1bf = bf16(M1); B1bf = bf16(M1 * W1)   (elementwise)
// ---------------------------------------------------------------------------
__global__ void post_m1_kernel(const float* __restrict__ M1,
                               const float* __restrict__ W1,
                               bf16* __restrict__ M1bf,
                               bf16* __restrict__ B1bf) {
    const size_t i = ((size_t)blockIdx.x * 256 + threadIdx.x) * 4;
    const float4 m = *(const float4*)&M1[i];
    const float4 w = *(const float4*)&W1[i];
    bf16x4 mb = {(bf16)m.x, (bf16)m.y, (bf16)m.z, (bf16)m.w};
    bf16x4 bb = {(bf16)(m.x * w.x), (bf16)(m.y * w.y),
                 (bf16)(m.z * w.z), (bf16)(m.w * w.w)};
    *(bf16x4*)&M1bf[i] = mb;
    *(bf16x4*)&B1bf[i] = bb;
}

// ---------------------------------------------------------------------------
// Epilogue: out = M1*M2 + M1 + M3 + M3*(M4*W1)*(M3 + M5)
// M2 already resides in `out`.
// ---------------------------------------------------------------------------
__global__ void epilogue_kernel(const float* __restrict__ M1,
                                const float* __restrict__ M3,
                                const float* __restrict__ M4,
                                const float* __restrict__ M5,
                                const float* __restrict__ W1,
                                float* __restrict__ out) {
    const size_t i = ((size_t)blockIdx.x * 256 + threadIdx.x) * 4;
    const float4 m1 = *(const float4*)&M1[i];
    const float4 m3 = *(const float4*)&M3[i];
    const float4 m4 = *(const float4*)&M4[i];
    const float4 m5 = *(const float4*)&M5[i];
    const float4 w1 = *(const float4*)&W1[i];
    const float4 m2 = *(const float4*)&out[i];
    float4 r;
    r.x = m1.x * m2.x + m1.x + m3.x + m3.x * (m4.x * w1.x) * (m3.x + m5.x);
    r.y = m1.y * m2.y + m1.y + m3.y + m3.y * (m4.y * w1.y) * (m3.y + m5.y);
    r.z = m1.z * m2.z + m1.z + m3.z + m3.z * (m4.z * w1.z) * (m3.z + m5.z);
    r.w = m1.w * m2.w + m1.w + m3.w + m3.w * (m4.w * w1.w) * (m3.w + m5.w);
    *(float4*)&out[i] = r;
}

// ---------------------------------------------------------------------------
extern "C" void kernel_launch(void* const* d_in, const int* in_sizes, int n_in,
                              void* d_out, int out_size, void* d_ws, size_t ws_size,
                              hipStream_t stream) {
    const float* A  = (const float*)d_in[0];
    const float* W1 = (const float*)d_in[1];
    const float* W2 = (const float*)d_in[2];
    const float* W3 = (const float*)d_in[3];
    float* out = (float*)d_out;

    const size_t P = (size_t)NN * NN;
    char* ws = (char*)d_ws;

    bf16* Abf  = (bf16*)ws;          // P*2 bytes each
    bf16* At   = Abf + P;
    bf16* W1t  = At + P;
    bf16* W2t  = W1t + P;            // reused as M1bf after batch-3 GEMM
    bf16* W3bf = W2t + P;            // reused as B1bf after batch-3 GEMM
    bf16* W3t  = W3bf + P;
    float* M1  = (float*)(W3t + P);  // P*4 bytes each
    float* M3  = M1 + P;
    float* M4  = M3 + P;
    float* M5  = M4 + P;
    // total: 6*2*P + 4*4*P = 28*P = 112 MiB

    const dim3 tb(32, 8), tg(NN / 32, NN / 32);
    // bf16 (and transposed-bf16) casts of the fp32 inputs
    transpose_cast_kernel<<<tg, tb, 0, stream>>>(A,  At,  Abf);
    transpose_cast_kernel<<<tg, tb, 0, stream>>>(W1, W1t, nullptr);
    transpose_cast_kernel<<<tg, tb, 0, stream>>>(W2, W2t, nullptr);
    transpose_cast_kernel<<<tg, tb, 0, stream>>>(W3, W3t, W3bf);

    // batch of 3 independent GEMMs: M1 = A@W1, M2(out) = A@W2, M3 = W3@W3
    GemmArgs g3;
    g3.A[0] = Abf;  g3.Bt[0] = W1t; g3.C[0] = M1;
    g3.A[1] = Abf;  g3.Bt[1] = W2t; g3.C[1] = out;
    g3.A[2] = W3bf; g3.Bt[2] = W3t; g3.C[2] = M3;
    gemm_bt_batched<<<dim3(NN / 128, NN / 128, 3), 256, 0, stream>>>(g3);

    // M1bf = bf16(M1), B1bf = bf16(M1*W1)  (reuse W2t / W3bf slots)
    bf16* M1bf = W2t;
    bf16* B1bf = W3bf;
    post_m1_kernel<<<(P / 4) / 256, 256, 0, stream>>>(M1, W1, M1bf, B1bf);

    // batch of 2 independent GEMMs: M5 = M1@A, M4 = (M1*W1)@A  (RHS = A -> At)
    GemmArgs g2;
    g2.A[0] = M1bf; g2.Bt[0] = At; g2.C[0] = M5;
    g2.A[1] = B1bf; g2.Bt[1] = At; g2.C[1] = M4;
    g2.A[2] = M1bf; g2.Bt[2] = At; g2.C[2] = M5;  // unused (z<2)
    gemm_bt_batched<<<dim3(NN / 128, NN / 128, 2), 256, 0, stream>>>(g2);

    // out = M1*M2 + M1 + M3 + M3*(M4*W1)*(M3+M5)
    epilogue_kernel<<<(P / 4) / 256, 256, 0, stream>>>(M1, M3, M4, M5, W1, out);
}

// Round 2
// 273.388 us; speedup vs baseline: 1.0612x; 1.0612x over previous
//
#include <hip/hip_runtime.h>
#include <hip/hip_bf16.h>
#include <stdint.h>

#define NN 2048
#define BM 128
#define BN 64
#define BK 32

typedef __bf16 bf16;
typedef __bf16 bf16x8 __attribute__((ext_vector_type(8)));
typedef __bf16 bf16x4 __attribute__((ext_vector_type(4)));
typedef float f32x4 __attribute__((ext_vector_type(4)));

// ---------------------------------------------------------------------------
// async global->LDS, 16B per lane (LDS dest = wave-uniform base + lane*16)
// ---------------------------------------------------------------------------
__device__ __forceinline__ void async_copy16(bf16* lds, const bf16* g) {
    __builtin_amdgcn_global_load_lds(
        (const __attribute__((address_space(1))) unsigned int*)g,
        (__attribute__((address_space(3))) unsigned int*)lds,
        16, 0, 0);
}

// ---------------------------------------------------------------------------
// fp32 -> bf16 transpose cast, z-batched over 4 inputs.
// outT[r][c] = (bf16) in[c][r];  outN[i] = (bf16) in[i] if outN != null
// block (32,8), grid (64,64,4)
// ---------------------------------------------------------------------------
struct CastArgs {
    const float* in[4];
    bf16*        outT[4];
    bf16*        outN[4];
};

__global__ void transpose_cast_kernel(CastArgs args) {
    const float* __restrict__ in = args.in[blockIdx.z];
    bf16* __restrict__ outT      = args.outT[blockIdx.z];
    bf16* __restrict__ outN      = args.outN[blockIdx.z];
    __shared__ float tile[32][33];
    const int bx = blockIdx.x * 32, by = blockIdx.y * 32;
    const int tx = threadIdx.x, ty = threadIdx.y;
#pragma unroll
    for (int i = 0; i < 32; i += 8) {
        float v = in[(size_t)(by + ty + i) * NN + bx + tx];
        tile[ty + i][tx] = v;
        if (outN) outN[(size_t)(by + ty + i) * NN + bx + tx] = (bf16)v;
    }
    __syncthreads();
#pragma unroll
    for (int i = 0; i < 32; i += 8)
        outT[(size_t)(bx + ty + i) * NN + by + tx] = (bf16)tile[tx][ty + i];
}

// ---------------------------------------------------------------------------
// Batched GEMM: C = A(row-major bf16) @ B with B given as Bt=B^T row-major.
// 128x64 tile, BK=32, 256 threads = 4 waves, each wave 64x32 via 4x2 MFMAs.
// LDS columns XOR-swizzled (8-elem blocks) to kill bank conflicts:
// physical block qp at row r holds logical block qp ^ ((r>>1)&3).
// ---------------------------------------------------------------------------
struct GemmArgs {
    const bf16* A[3];
    const bf16* Bt[3];
    float*      C[3];
};

__global__ __launch_bounds__(256) void gemm_bt_batched(GemmArgs args) {
    const bf16* __restrict__ A  = args.A[blockIdx.z];
    const bf16* __restrict__ Bt = args.Bt[blockIdx.z];
    float* __restrict__ C       = args.C[blockIdx.z];

    __shared__ bf16 As[BM * BK];   // 8 KB
    __shared__ bf16 Bs[BN * BK];   // 4 KB

    const int t  = threadIdx.x;          // 0..255
    const int bm = blockIdx.x * BM;
    const int bn = blockIdx.y * BN;

    // staging: thread t -> LDS slot (row0 = t>>2, physical block qp = t&3),
    // fetches global column block (qp ^ ((row0>>1)&3))
    const int row0 = t >> 2;             // 0..63
    const int qp   = t & 3;
    const int col0 = ((qp ^ ((row0 >> 1) & 3)) << 3);
    const int off0 = t * 8;              // linear LDS elem offset

    const bf16* gA0 = A  + (size_t)(bm + row0) * NN + col0;
    const bf16* gB0 = Bt + (size_t)(bn + row0) * NN + col0;

    const int wave = t >> 6;
    const int lane = t & 63;
    const int wm   = (wave >> 1) * 64;   // 0 or 64
    const int wn   = (wave & 1) * 32;    // 0 or 32
    const int lrow = lane & 15;
    const int q    = lane >> 4;          // 0..3
    const int qe   = (q ^ ((lrow >> 1) & 3)) << 3;  // swizzled read column

    f32x4 acc[4][2];
#pragma unroll
    for (int i = 0; i < 4; ++i)
#pragma unroll
        for (int j = 0; j < 2; ++j) acc[i][j] = (f32x4){0.f, 0.f, 0.f, 0.f};

    for (int k0 = 0; k0 < NN; k0 += BK) {
        async_copy16(&As[off0],           gA0 + k0);
        async_copy16(&As[off0 + 64 * BK], gA0 + (size_t)64 * NN + k0);
        async_copy16(&Bs[off0],           gB0 + k0);
        __syncthreads();

        bf16x8 af[4], bfr[2];
#pragma unroll
        for (int i = 0; i < 4; ++i)
            af[i] = *(const bf16x8*)&As[(wm + i * 16 + lrow) * BK + qe];
#pragma unroll
        for (int j = 0; j < 2; ++j)
            bfr[j] = *(const bf16x8*)&Bs[(wn + j * 16 + lrow) * BK + qe];

#pragma unroll
        for (int i = 0; i < 4; ++i)
#pragma unroll
            for (int j = 0; j < 2; ++j)
                acc[i][j] = __builtin_amdgcn_mfma_f32_16x16x32_bf16(
                    af[i], bfr[j], acc[i][j], 0, 0, 0);
        __syncthreads();
    }

    // C/D layout: col = lane&15, row = q*4 + reg
#pragma unroll
    for (int i = 0; i < 4; ++i)
#pragma unroll
        for (int j = 0; j < 2; ++j)
#pragma unroll
            for (int r = 0; r < 4; ++r)
                C[(size_t)(bm + wm + i * 16 + q * 4 + r) * NN +
                  (bn + wn + j * 16 + lrow)] = acc[i][j][r];
}

// ---------------------------------------------------------------------------
// M1 post-pass: M1bf = bf16(M1); B1bf = bf16(M1 * W1)
// ---------------------------------------------------------------------------
__global__ void post_m1_kernel(const float* __restrict__ M1,
                               const float* __restrict__ W1,
                               bf16* __restrict__ M1bf,
                               bf16* __restrict__ B1bf) {
    const size_t i = ((size_t)blockIdx.x * 256 + threadIdx.x) * 4;
    const float4 m = *(const float4*)&M1[i];
    const float4 w = *(const float4*)&W1[i];
    bf16x4 mb = {(bf16)m.x, (bf16)m.y, (bf16)m.z, (bf16)m.w};
    bf16x4 bb = {(bf16)(m.x * w.x), (bf16)(m.y * w.y),
                 (bf16)(m.z * w.z), (bf16)(m.w * w.w)};
    *(bf16x4*)&M1bf[i] = mb;
    *(bf16x4*)&B1bf[i] = bb;
}

// ---------------------------------------------------------------------------
// Epilogue: out = M1*M2 + M1 + M3 + M3*(M4*W1)*(M3 + M5); M2 resides in out.
// ---------------------------------------------------------------------------
__global__ void epilogue_kernel(const float* __restrict__ M1,
                                const float* __restrict__ M3,
                                const float* __restrict__ M4,
                                const float* __restrict__ M5,
                                const float* __restrict__ W1,
                                float* __restrict__ out) {
    const size_t i = ((size_t)blockIdx.x * 256 + threadIdx.x) * 4;
    const float4 m1 = *(const float4*)&M1[i];
    const float4 m3 = *(const float4*)&M3[i];
    const float4 m4 = *(const float4*)&M4[i];
    const float4 m5 = *(const float4*)&M5[i];
    const float4 w1 = *(const float4*)&W1[i];
    const float4 m2 = *(const float4*)&out[i];
    float4 r;
    r.x = m1.x * m2.x + m1.x + m3.x + m3.x * (m4.x * w1.x) * (m3.x + m5.x);
    r.y = m1.y * m2.y + m1.y + m3.y + m3.y * (m4.y * w1.y) * (m3.y + m5.y);
    r.z = m1.z * m2.z + m1.z + m3.z + m3.z * (m4.z * w1.z) * (m3.z + m5.z);
    r.w = m1.w * m2.w + m1.w + m3.w + m3.w * (m4.w * w1.w) * (m3.w + m5.w);
    *(float4*)&out[i] = r;
}

// ---------------------------------------------------------------------------
extern "C" void kernel_launch(void* const* d_in, const int* in_sizes, int n_in,
                              void* d_out, int out_size, void* d_ws, size_t ws_size,
                              hipStream_t stream) {
    const float* A  = (const float*)d_in[0];
    const float* W1 = (const float*)d_in[1];
    const float* W2 = (const float*)d_in[2];
    const float* W3 = (const float*)d_in[3];
    float* out = (float*)d_out;

    const size_t P = (size_t)NN * NN;
    char* ws = (char*)d_ws;

    bf16* Abf  = (bf16*)ws;          // P*2 bytes each
    bf16* At   = Abf + P;
    bf16* W1t  = At + P;
    bf16* W2t  = W1t + P;            // reused as M1bf after phase-1 GEMM
    bf16* W3bf = W2t + P;            // reused as B1bf after phase-1 GEMM
    bf16* W3t  = W3bf + P;
    float* M1  = (float*)(W3t + P);  // P*4 bytes each
    float* M3  = M1 + P;
    float* M4  = M3 + P;
    float* M5  = M4 + P;
    // total: 6*2*P + 4*4*P = 28*P = 112 MiB

    // one z-batched launch: bf16 (and transposed-bf16) casts of all 4 inputs
    CastArgs ca;
    ca.in[0] = A;  ca.outT[0] = At;  ca.outN[0] = Abf;
    ca.in[1] = W1; ca.outT[1] = W1t; ca.outN[1] = nullptr;
    ca.in[2] = W2; ca.outT[2] = W2t; ca.outN[2] = nullptr;
    ca.in[3] = W3; ca.outT[3] = W3t; ca.outN[3] = W3bf;
    transpose_cast_kernel<<<dim3(NN / 32, NN / 32, 4), dim3(32, 8), 0, stream>>>(ca);

    // phase 1 (3 GEMMs): M1 = A@W1, M2(out) = A@W2, M3 = W3@W3
    GemmArgs g3;
    g3.A[0] = Abf;  g3.Bt[0] = W1t; g3.C[0] = M1;
    g3.A[1] = Abf;  g3.Bt[1] = W2t; g3.C[1] = out;
    g3.A[2] = W3bf; g3.Bt[2] = W3t; g3.C[2] = M3;
    gemm_bt_batched<<<dim3(NN / BM, NN / BN, 3), 256, 0, stream>>>(g3);

    // M1bf = bf16(M1), B1bf = bf16(M1*W1)  (reuse W2t / W3bf slots)
    bf16* M1bf = W2t;
    bf16* B1bf = W3bf;
    post_m1_kernel<<<(P / 4) / 256, 256, 0, stream>>>(M1, W1, M1bf, B1bf);

    // phase 2 (2 GEMMs): M5 = M1@A, M4 = (M1*W1)@A  (RHS = A -> At)
    GemmArgs g2;
    g2.A[0] = M1bf; g2.Bt[0] = At; g2.C[0] = M5;
    g2.A[1] = B1bf; g2.Bt[1] = At; g2.C[1] = M4;
    g2.A[2] = M1bf; g2.Bt[2] = At; g2.C[2] = M5;  // unused (z<2)
    gemm_bt_batched<<<dim3(NN / BM, NN / BN, 2), 256, 0, stream>>>(g2);

    // out = M1*M2 + M1 + M3 + M3*(M4*W1)*(M3+M5)
    epilogue_kernel<<<(P / 4) / 256, 256, 0, stream>>>(M1, M3, M4, M5, W1, out);
}

// Round 4
// 237.582 us; speedup vs baseline: 1.2211x; 1.1507x over previous
//
#include <hip/hip_runtime.h>
#include <hip/hip_bf16.h>
#include <stdint.h>

#define NN 2048
#define BM 128
#define BN 128
#define BK 32

typedef __bf16 bf16;
typedef __bf16 bf16x8 __attribute__((ext_vector_type(8)));
typedef __bf16 bf16x4 __attribute__((ext_vector_type(4)));
typedef float f32x4 __attribute__((ext_vector_type(4)));

// async global->LDS, 16B per lane (LDS dest = wave-uniform base + lane*16)
__device__ __forceinline__ void async_copy16(bf16* lds, const bf16* g) {
    __builtin_amdgcn_global_load_lds(
        (const __attribute__((address_space(1))) unsigned int*)g,
        (__attribute__((address_space(3))) unsigned int*)lds,
        16, 0, 0);
}

// fine-grained waits + compiler-visible raw barrier (no vmcnt(0) drain)
#define WAIT_VM8() asm volatile("s_waitcnt vmcnt(8)" ::: "memory")
#define WAIT_VM4() asm volatile("s_waitcnt vmcnt(4)" ::: "memory")
#define WAIT_VM0() asm volatile("s_waitcnt vmcnt(0)" ::: "memory")
#define BAR()                                  \
    do {                                       \
        asm volatile("" ::: "memory");         \
        __builtin_amdgcn_s_barrier();          \
        asm volatile("" ::: "memory");         \
    } while (0)

// ---------------------------------------------------------------------------
// fp32 -> bf16 transpose cast, z-batched. 64x64 tile, 256 threads.
// outT[c][r] = (bf16) in[r][c];  outN = straight bf16 cast (optional)
// ---------------------------------------------------------------------------
struct CastArgs {
    const float* in[4];
    bf16*        outT[4];
    bf16*        outN[4];
};

__global__ __launch_bounds__(256) void transpose_cast_kernel(CastArgs args) {
    const float* __restrict__ in = args.in[blockIdx.z];
    bf16* __restrict__ outT      = args.outT[blockIdx.z];
    bf16* __restrict__ outN      = args.outN[blockIdx.z];
    __shared__ float tile[64][65];
    const int bx = blockIdx.x * 64;   // col base
    const int by = blockIdx.y * 64;   // row base
    const int t  = threadIdx.x;
    const int tc = t & 15, tr = t >> 4;
#pragma unroll
    for (int p = 0; p < 4; ++p) {
        const int r = tr + p * 16;
        const float4 v = *(const float4*)&in[(size_t)(by + r) * NN + bx + tc * 4];
        tile[r][tc * 4 + 0] = v.x; tile[r][tc * 4 + 1] = v.y;
        tile[r][tc * 4 + 2] = v.z; tile[r][tc * 4 + 3] = v.w;
        if (outN) {
            bf16x4 b = {(bf16)v.x, (bf16)v.y, (bf16)v.z, (bf16)v.w};
            *(bf16x4*)&outN[(size_t)(by + r) * NN + bx + tc * 4] = b;
        }
    }
    __syncthreads();
    const int cc = t >> 2, e = t & 3;
#pragma unroll
    for (int u = 0; u < 2; ++u) {
        const int r0 = e * 16 + u * 8;
        bf16x8 b;
#pragma unroll
        for (int i = 0; i < 8; ++i) b[i] = (bf16)tile[r0 + i][cc];
        *(bf16x8*)&outT[(size_t)(bx + cc) * NN + by + r0] = b;
    }
}

// ---------------------------------------------------------------------------
// Batched GEMM: C = A @ B, B given as Bt = B^T row-major. bf16 in, fp32 out.
// 128x128 tile, BK=32, 4 waves, each wave 64x64 (4x4 16x16x32 MFMAs).
// Software-pipelined depth-3: 3 separate LDS buffer pairs, explicit
// s_waitcnt vmcnt(8) + raw s_barrier — prefetches stay in flight across
// barriers (no vmcnt(0) drain). XOR-swizzled LDS columns: 0 bank conflicts.
// ---------------------------------------------------------------------------
struct GemmArgs {
    const bf16* A[3];
    const bf16* Bt[3];
    float*      C[3];
};

__global__ __launch_bounds__(256) void gemm_bt_batched(GemmArgs args) {
    const bf16* __restrict__ A  = args.A[blockIdx.z];
    const bf16* __restrict__ Bt = args.Bt[blockIdx.z];
    float* __restrict__ C       = args.C[blockIdx.z];

    // separate objects -> precise alias info for the LDS-DMA hazard pass
    __shared__ bf16 As0[BM * BK], As1[BM * BK], As2[BM * BK];
    __shared__ bf16 Bs0[BN * BK], Bs1[BN * BK], Bs2[BN * BK];

    const int t  = threadIdx.x;
    const int bm = blockIdx.x * BM;
    const int bn = blockIdx.y * BN;

    // staging: thread t -> LDS slot (row0 = t>>2, block qp = t&3); the lane
    // fetches global column block (qp ^ ((row0>>1)&3))  [XOR swizzle]
    const int row0 = t >> 2;
    const int qp   = t & 3;
    const int col0 = ((qp ^ ((row0 >> 1) & 3)) << 3);
    const int off0 = t * 8;

    const bf16* gA0 = A  + (size_t)(bm + row0) * NN + col0;
    const bf16* gB0 = Bt + (size_t)(bn + row0) * NN + col0;

    const int wave = t >> 6;
    const int lane = t & 63;
    const int wm   = (wave >> 1) * 64;
    const int wn   = (wave & 1) * 64;
    const int lrow = lane & 15;
    const int q    = lane >> 4;
    const int qe   = (q ^ ((lrow >> 1) & 3)) << 3;  // swizzled read column

    f32x4 acc[4][4];
#pragma unroll
    for (int i = 0; i < 4; ++i)
#pragma unroll
        for (int j = 0; j < 4; ++j) acc[i][j] = (f32x4){0.f, 0.f, 0.f, 0.f};

    auto issue = [&](bf16* As, bf16* Bs, int kt) {
        const int kof = kt * BK;
        async_copy16(&As[off0],           gA0 + kof);
        async_copy16(&As[off0 + 64 * BK], gA0 + (size_t)64 * NN + kof);
        async_copy16(&Bs[off0],           gB0 + kof);
        async_copy16(&Bs[off0 + 64 * BK], gB0 + (size_t)64 * NN + kof);
    };
    auto compute = [&](const bf16* As, const bf16* Bs) {
        bf16x8 af[4], bfr[4];
#pragma unroll
        for (int i = 0; i < 4; ++i)
            af[i] = *(const bf16x8*)&As[(wm + i * 16 + lrow) * BK + qe];
#pragma unroll
        for (int j = 0; j < 4; ++j)
            bfr[j] = *(const bf16x8*)&Bs[(wn + j * 16 + lrow) * BK + qe];
#pragma unroll
        for (int i = 0; i < 4; ++i)
#pragma unroll
            for (int j = 0; j < 4; ++j)
                acc[i][j] = __builtin_amdgcn_mfma_f32_16x16x32_bf16(
                    af[i], bfr[j], acc[i][j], 0, 0, 0);
    };

    // prologue: tiles 0,1 in flight (8 loads outstanding per wave)
    issue(As0, Bs0, 0);
    issue(As1, Bs1, 1);

    // steady state: issue tile k+2, wait tile k (leave 8 in flight), compute
#pragma unroll 1
    for (int kt = 0; kt < 60; kt += 3) {
        issue(As2, Bs2, kt + 2); WAIT_VM8(); BAR(); compute(As0, Bs0); BAR();
        issue(As0, Bs0, kt + 3); WAIT_VM8(); BAR(); compute(As1, Bs1); BAR();
        issue(As1, Bs1, kt + 4); WAIT_VM8(); BAR(); compute(As2, Bs2); BAR();
    }
    // tiles 60..63 (tail)
    issue(As2, Bs2, 62); WAIT_VM8(); BAR(); compute(As0, Bs0); BAR();
    issue(As0, Bs0, 63); WAIT_VM8(); BAR(); compute(As1, Bs1); BAR();
    WAIT_VM4(); BAR(); compute(As2, Bs2); BAR();
    WAIT_VM0(); BAR(); compute(As0, Bs0);

    // C/D layout: col = lane&15, row = q*4 + reg
#pragma unroll
    for (int i = 0; i < 4; ++i)
#pragma unroll
        for (int j = 0; j < 4; ++j)
#pragma unroll
            for (int r = 0; r < 4; ++r)
                C[(size_t)(bm + wm + i * 16 + q * 4 + r) * NN +
                  (bn + wn + j * 16 + lrow)] = acc[i][j][r];
}

// ---------------------------------------------------------------------------
// M1 post-pass: M1bf = bf16(M1); B1bf = bf16(M1 * W1)
// ---------------------------------------------------------------------------
__global__ void post_m1_kernel(const float* __restrict__ M1,
                               const float* __restrict__ W1,
                               bf16* __restrict__ M1bf,
                               bf16* __restrict__ B1bf) {
    const size_t i = ((size_t)blockIdx.x * 256 + threadIdx.x) * 4;
    const float4 m = *(const float4*)&M1[i];
    const float4 w = *(const float4*)&W1[i];
    bf16x4 mb = {(bf16)m.x, (bf16)m.y, (bf16)m.z, (bf16)m.w};
    bf16x4 bb = {(bf16)(m.x * w.x), (bf16)(m.y * w.y),
                 (bf16)(m.z * w.z), (bf16)(m.w * w.w)};
    *(bf16x4*)&M1bf[i] = mb;
    *(bf16x4*)&B1bf[i] = bb;
}

// ---------------------------------------------------------------------------
// Epilogue: out = M1*M2 + M1 + M3 + M3*(M4*W1)*(M3 + M5); M2 resides in out.
// ---------------------------------------------------------------------------
__global__ void epilogue_kernel(const float* __restrict__ M1,
                                const float* __restrict__ M3,
                                const float* __restrict__ M4,
                                const float* __restrict__ M5,
                                const float* __restrict__ W1,
                                float* __restrict__ out) {
    const size_t i = ((size_t)blockIdx.x * 256 + threadIdx.x) * 4;
    const float4 m1 = *(const float4*)&M1[i];
    const float4 m3 = *(const float4*)&M3[i];
    const float4 m4 = *(const float4*)&M4[i];
    const float4 m5 = *(const float4*)&M5[i];
    const float4 w1 = *(const float4*)&W1[i];
    const float4 m2 = *(const float4*)&out[i];
    float4 r;
    r.x = m1.x * m2.x + m1.x + m3.x + m3.x * (m4.x * w1.x) * (m3.x + m5.x);
    r.y = m1.y * m2.y + m1.y + m3.y + m3.y * (m4.y * w1.y) * (m3.y + m5.y);
    r.z = m1.z * m2.z + m1.z + m3.z + m3.z * (m4.z * w1.z) * (m3.z + m5.z);
    r.w = m1.w * m2.w + m1.w + m3.w + m3.w * (m4.w * w1.w) * (m3.w + m5.w);
    *(float4*)&out[i] = r;
}

// ---------------------------------------------------------------------------
extern "C" void kernel_launch(void* const* d_in, const int* in_sizes, int n_in,
                              void* d_out, int out_size, void* d_ws, size_t ws_size,
                              hipStream_t stream) {
    const float* A  = (const float*)d_in[0];
    const float* W1 = (const float*)d_in[1];
    const float* W2 = (const float*)d_in[2];
    const float* W3 = (const float*)d_in[3];
    float* out = (float*)d_out;

    const size_t P = (size_t)NN * NN;
    char* ws = (char*)d_ws;

    bf16* Abf  = (bf16*)ws;          // P*2 bytes each
    bf16* At   = Abf + P;
    bf16* W1t  = At + P;
    bf16* W2t  = W1t + P;            // reused as M1bf after phase-1 GEMM
    bf16* W3bf = W2t + P;            // reused as B1bf after phase-1 GEMM
    bf16* W3t  = W3bf + P;
    float* M1  = (float*)(W3t + P);  // P*4 bytes each
    float* M3  = M1 + P;
    float* M4  = M3 + P;
    float* M5  = M4 + P;
    // total: 6*2*P + 4*4*P = 28*P = 112 MiB

    CastArgs ca;
    ca.in[0] = A;  ca.outT[0] = At;  ca.outN[0] = Abf;
    ca.in[1] = W1; ca.outT[1] = W1t; ca.outN[1] = nullptr;
    ca.in[2] = W2; ca.outT[2] = W2t; ca.outN[2] = nullptr;
    ca.in[3] = W3; ca.outT[3] = W3t; ca.outN[3] = W3bf;
    transpose_cast_kernel<<<dim3(NN / 64, NN / 64, 4), 256, 0, stream>>>(ca);

    // phase 1 (3 GEMMs): M1 = A@W1, M2(out) = A@W2, M3 = W3@W3
    GemmArgs g3;
    g3.A[0] = Abf;  g3.Bt[0] = W1t; g3.C[0] = M1;
    g3.A[1] = Abf;  g3.Bt[1] = W2t; g3.C[1] = out;
    g3.A[2] = W3bf; g3.Bt[2] = W3t; g3.C[2] = M3;
    gemm_bt_batched<<<dim3(NN / BM, NN / BN, 3), 256, 0, stream>>>(g3);

    // M1bf = bf16(M1), B1bf = bf16(M1*W1)  (reuse W2t / W3bf slots)
    bf16* M1bf = W2t;
    bf16* B1bf = W3bf;
    post_m1_kernel<<<(P / 4) / 256, 256, 0, stream>>>(M1, W1, M1bf, B1bf);

    // phase 2 (2 GEMMs): M5 = M1@A, M4 = (M1*W1)@A  (RHS = A -> At)
    GemmArgs g2;
    g2.A[0] = M1bf; g2.Bt[0] = At; g2.C[0] = M5;
    g2.A[1] = B1bf; g2.Bt[1] = At; g2.C[1] = M4;
    g2.A[2] = M1bf; g2.Bt[2] = At; g2.C[2] = M5;  // unused (z<2)
    gemm_bt_batched<<<dim3(NN / BM, NN / BN, 2), 256, 0, stream>>>(g2);

    // out = M1*M2 + M1 + M3 + M3*(M4*W1)*(M3+M5)
    epilogue_kernel<<<(P / 4) / 256, 256, 0, stream>>>(M1, M3, M4, M5, W1, out);
}